// Round 10
// baseline (1715.466 us; speedup 1.0000x reference)
//
#include <hip/hip_runtime.h>
#include <hip/hip_fp16.h>
#include <stdint.h>

// ---------- types ----------
typedef _Float16 half8 __attribute__((ext_vector_type(8)));
typedef _Float16 h2v __attribute__((ext_vector_type(2)));
typedef float f32x16 __attribute__((ext_vector_type(16)));

#define GLD_LDS16(gp, lp)                                                     \
  __builtin_amdgcn_global_load_lds(                                           \
      (const __attribute__((address_space(1))) void*)(gp),                    \
      (__attribute__((address_space(3))) void*)(lp), 16, 0, 0)
#define GLD_LDS4(gp, lp)                                                      \
  __builtin_amdgcn_global_load_lds(                                           \
      (const __attribute__((address_space(1))) void*)(gp),                    \
      (__attribute__((address_space(3))) void*)(lp), 4, 0, 0)

// ---------- x convert: fp32 (harness upcast) -> fp16 ----------
__global__ void xcvt_kernel(const float* __restrict__ in, __half* __restrict__ out) {
  const size_t i = ((size_t)blockIdx.x * 256 + threadIdx.x) * 4;
  float4 v = *(const float4*)(in + i);
  __half2* o = (__half2*)(out + i);
  o[0] = __floats2half2_rn(v.x, v.y);
  o[1] = __floats2half2_rn(v.z, v.w);
}

// ---------- repack: qweight [K][N/8] col-packed -> [K/8][N] k-packed ----------
// Output dword for (q, n): nibble of k=8q+t placed at bits 4*(t>>1) + 16*(t&1),
// so that (p >> 4j) & 0x000F000F gives halves (k=2j, k=2j+1).
__global__ void repack_kernel(const int* __restrict__ qw, uint32_t* __restrict__ rp, int P) {
  const int N = P * 8;
  const int n = blockIdx.x * 256 + threadIdx.x;
  const int j8 = n >> 3;
  const int sh = (n & 7) * 4;
  #pragma unroll
  for (int qi = 0; qi < 4; ++qi) {
    const int q = blockIdx.y * 4 + qi;
    const int* src = qw + (size_t)(q * 8) * P + j8;
    uint32_t r = 0;
    #pragma unroll
    for (int t = 0; t < 8; ++t) {
      uint32_t w = ((uint32_t)src[t * P] >> sh) & 15u;
      r |= w << (4 * (t >> 1) + 16 * (t & 1));
    }
    rp[(size_t)q * N + n] = r;
  }
}

// ---------- smz: per (group, col) pack (s_bits, (1024+z)_bits) ----------
__global__ void smz_kernel(const float* __restrict__ sc, const int* __restrict__ qz,
                           uint32_t* __restrict__ smz, int P) {
  const int N = P * 8;
  const int n = blockIdx.x * 256 + threadIdx.x;
  const int g = blockIdx.y;
  uint32_t sbits = __half_as_ushort(__float2half(sc[(size_t)g * N + n]));  // exact
  uint32_t z = ((uint32_t)qz[(size_t)g * P + (n >> 3)] >> ((n & 7) * 4)) & 15u;
  uint32_t hz = 0x6400u | z;  // fp16(1024+z), exact
  smz[(size_t)g * N + n] = sbits | (hz << 16);
}

// ---------- dequant 8 nibbles -> half8 (pk-f16 ops) ----------
union U32H2 { uint32_t u; h2v h; };
__device__ inline h2v bith2(uint32_t u) { U32H2 t; t.u = u; return t.h; }
__device__ inline uint32_t h2bit(h2v h) { U32H2 t; t.h = h; return t.u; }
__device__ inline half8 dequant8(uint32_t p, h2v s, h2v z) {
  union { uint32_t u[4]; half8 v; } r;
  r.u[0] = h2bit((bith2((p & 0x000F000Fu) | 0x64006400u) - z) * s);
  r.u[1] = h2bit((bith2(((p >> 4) & 0x000F000Fu) | 0x64006400u) - z) * s);
  r.u[2] = h2bit((bith2(((p >> 8) & 0x000F000Fu) | 0x64006400u) - z) * s);
  r.u[3] = h2bit((bith2(((p >> 12) & 0x000F000Fu) | 0x64006400u) - z) * s);
  return r.v;  // v_pk_sub_f16 (exact) + v_pk_mul_f16 (1 rounding) per dword
}

// ---------- fused AWQ GEMM (32x32x16 MFMA) ----------
// Block: 128 rows x NT tiles of 128 cols (tile tl at n0 + tl*T1OFF,
// n0 = blockIdx.x * BXS). 4 waves, 1x4 col split: wave owns cols
// wv*32..+31 of BOTH tiles, all 128 rows (dequant amortized over 4 rowfrags
// of 32 = same 64-col-per-wave dequant volume as the proven R7 structure).
// MFMA 32x32x16: per K-step per wave = 4 kf x (2 tl x 4 rf) = 32 MFMAs.
// Fragment layouts: A/B input: row/col = lane&31, k = kf*16 + (lane>>5)*8 + j.
// C/D: col = lane&31, row = (reg&3) + 8*(reg>>2) + 4*(lane>>5)  [m74/m101].
// B: one repacked dword IS the lane's 8-k slice -> linear LDS, no swizzle,
// 2 lanes/bank (free). A: proven XOR-swizzled staging unchanged.
// Triple-buffered staging, one s_barrier per K-step preceded by COUNTED
// s_waitcnt vmcnt(6/7) (batch = 4A + NT B + smz-on-even; identical to R7/R9).
template <int KDIM, int NW, int T1OFF, int OW, bool SILU, int NT, int BXS>
__global__ __launch_bounds__(256, 2) void awq_gemm(const __half* __restrict__ A,
                                                   const uint32_t* __restrict__ RP,
                                                   const uint32_t* __restrict__ SMZ,
                                                   void* __restrict__ OUT) {
  constexpr int ABUF = 128 * 64 * 2;          // 16384 B per A buffer
  constexpr int BBUF = NT * 8 * 128 * 4;      // 4096*NT per B buffer
  constexpr int BOFF = 3 * ABUF;              // 49152
  constexpr int ZOFF = BOFF + 3 * BBUF;       // smz double buffer (2 x 1024 B)
  __shared__ __align__(16) unsigned char smem[ZOFF + 2048];

  const int tid = threadIdx.x;
  const int l = tid & 63;
  const int wv = tid >> 6;
  const int l31 = l & 31;
  const int lh = l >> 5;        // k-half selector

  const int row0 = blockIdx.y * 128;
  const int n0 = blockIdx.x * BXS;

  // A staging sources (swizzled: LDS chunk slot c at row m holds k-chunk c^(m&7))
  const __half* asrc[4];
  #pragma unroll
  for (int it = 0; it < 4; ++it) {
    int m = it * 32 + (tid >> 3);
    int cs = tid & 7;
    int kc = cs ^ (m & 7);
    asrc[it] = A + (size_t)(row0 + m) * KDIM + kc * 8;
  }

  // B staging sources: LINEAR. Thread tid covers (qr = (tid>>5)&7, colq = tid&31):
  // LDS slot tid*16 of tile tl = dwords for qrow qr, cols colq*4..+3.
  const uint32_t* bsrc[NT];
  #pragma unroll
  for (int tl = 0; tl < NT; ++tl)
    bsrc[tl] = RP + (size_t)((tid >> 5) & 7) * NW + n0 + tl * T1OFF + (tid & 31) * 4;

  // SMZ staging source: thread covers (tile = tid>>7, col offset tid&127)
  const uint32_t* zsrc = SMZ + n0 + (size_t)(tid >> 7) * T1OFF + (tid & 127);

  f32x16 acc[NT][4];  // [tile][rowfrag]
  #pragma unroll
  for (int tl = 0; tl < NT; ++tl)
    #pragma unroll
    for (int rf = 0; rf < 4; ++rf)
      #pragma unroll
      for (int e = 0; e < 16; ++e) acc[tl][rf][e] = 0.f;

  uint32_t s2[NT], z2[NT];
  constexpr int NSTEP = KDIM / 64;

  // lane-constant offsets
  // A read: row = rf*32 + l31, chunk = (kf*2 + lh) ^ (row&7) = (kf*2+lh) ^ (l31&7)
  // B read: tile tl, kf: dword (qr = kf*2+lh, col = wv*32+l31)
  const int bbase_l = (wv * 32 + l31) * 4;
  const int achunk_x = l31 & 7;
  const int arow_off = l31 * 128;

  // ---- prologue: batch(0) [A,B,smz g0] then batch(1) [A,B] ----
  #pragma unroll
  for (int it = 0; it < 4; ++it)
    GLD_LDS16(asrc[it], &smem[it * 4096 + tid * 16]);
  #pragma unroll
  for (int tl = 0; tl < NT; ++tl)
    GLD_LDS16(bsrc[tl], &smem[BOFF + tl * 4096 + tid * 16]);
  GLD_LDS4(zsrc, &smem[ZOFF + tid * 4]);
  #pragma unroll
  for (int it = 0; it < 4; ++it)
    GLD_LDS16(asrc[it] + 64, &smem[ABUF + it * 4096 + tid * 16]);
  #pragma unroll
  for (int tl = 0; tl < NT; ++tl)
    GLD_LDS16(bsrc[tl] + (size_t)8 * NW, &smem[BOFF + BBUF + tl * 4096 + tid * 16]);

  int cur = 0, stg = 2;  // buf(t%3), buf((t+2)%3)
  for (int t = 0; t < NSTEP; ++t) {
    // counted wait: drain batch(t); batch(t+1) = 6 (+1 if t+1 even) in flight
    if (t == NSTEP - 1)      asm volatile("s_waitcnt vmcnt(0)" ::: "memory");
    else if (t & 1)          asm volatile("s_waitcnt vmcnt(7)" ::: "memory");
    else                     asm volatile("s_waitcnt vmcnt(6)" ::: "memory");
    __builtin_amdgcn_s_barrier();

    // issue batch(t+2) into buf stg
    if (t + 2 < NSTEP) {
      #pragma unroll
      for (int it = 0; it < 4; ++it)
        GLD_LDS16(asrc[it] + (size_t)(t + 2) * 64, &smem[stg * ABUF + it * 4096 + tid * 16]);
      #pragma unroll
      for (int tl = 0; tl < NT; ++tl)
        GLD_LDS16(bsrc[tl] + (size_t)(t + 2) * 8 * NW,
                  &smem[BOFF + stg * BBUF + tl * 4096 + tid * 16]);
      if (((t + 2) & 1) == 0) {  // smz for group (t+2)/2 into buf ((t+2)/2)&1
        const int g = (t + 2) >> 1;
        GLD_LDS4(zsrc + (size_t)g * NW, &smem[ZOFF + (g & 1) * 1024 + tid * 4]);
      }
    }

    if ((t & 1) == 0) {  // group boundary: unpack s/z (col = wv*32 + l31)
      const uint32_t* zl = (const uint32_t*)&smem[ZOFF + ((t >> 1) & 1) * 1024];
      #pragma unroll
      for (int tl = 0; tl < NT; ++tl) {
        uint32_t u = zl[tl * 128 + wv * 32 + l31];
        uint32_t lo = u & 0xFFFFu;
        s2[tl] = lo | (lo << 16);
        z2[tl] = (u & 0xFFFF0000u) | (u >> 16);
      }
    }

    // B dwords: linear layout, (tile, kf) -> qr = kf*2+lh
    uint32_t bq[NT][4];
    const unsigned char* bbase = &smem[BOFF + cur * BBUF];
    #pragma unroll
    for (int tl = 0; tl < NT; ++tl)
      #pragma unroll
      for (int kf = 0; kf < 4; ++kf)
        bq[tl][kf] = *(const uint32_t*)&bbase[tl * 4096 + (kf * 2 + lh) * 512 + bbase_l];

    const unsigned char* abase = &smem[cur * ABUF];
    #pragma unroll
    for (int kf = 0; kf < 4; ++kf) {
      half8 a[4];
      const int chunk = ((kf * 2 + lh) ^ achunk_x) * 16;
      #pragma unroll
      for (int rf = 0; rf < 4; ++rf)
        a[rf] = *(const half8*)(abase + rf * 4096 + arow_off + chunk);
      #pragma unroll
      for (int tl = 0; tl < NT; ++tl) {
        half8 b = dequant8(bq[tl][kf], bith2(s2[tl]), bith2(z2[tl]));
        #pragma unroll
        for (int rf = 0; rf < 4; ++rf)
          acc[tl][rf] =
              __builtin_amdgcn_mfma_f32_32x32x16_f16(a[rf], b, acc[tl][rf], 0, 0, 0);
      }
    }

    cur = (cur == 2) ? 0 : cur + 1;
    stg = (stg == 2) ? 0 : stg + 1;
  }

  // epilogue: C/D layout: col = l31, row = rf*32 + (reg&3) + 8*(reg>>2) + 4*lh
  if (SILU) {
    __half* O = (__half*)OUT;
    #pragma unroll
    for (int rf = 0; rf < 4; ++rf)
      #pragma unroll
      for (int reg = 0; reg < 16; ++reg) {
        int row = row0 + rf * 32 + (reg & 3) + 8 * (reg >> 2) + 4 * lh;
        int col = n0 + wv * 32 + l31;
        float gf = __half2float(__float2half(acc[0][rf][reg]));  // gate fp16 cast
        float uf = __half2float(__float2half(acc[1][rf][reg]));  // up fp16 cast
        float sig = 1.f / (1.f + __expf(-gf));
        float sil = __half2float(__float2half(gf * sig));        // silu fp16 cast
        O[(size_t)row * OW + col] = __float2half(sil * uf);      // intermediate fp16
      }
  } else {
    float* O = (float*)OUT;
    #pragma unroll
    for (int tl = 0; tl < NT; ++tl)
      #pragma unroll
      for (int rf = 0; rf < 4; ++rf)
        #pragma unroll
        for (int reg = 0; reg < 16; ++reg) {
          int row = row0 + rf * 32 + (reg & 3) + 8 * (reg >> 2) + 4 * lh;
          int col = n0 + tl * T1OFF + wv * 32 + l31;
          O[(size_t)row * OW + col] = __half2float(__float2half(acc[tl][rf][reg]));
        }
  }
}

// ---------- launch ----------
// Workspace phase-aliasing (stay under round-1-proven-safe 263,397,376 B):
//   phase 1 (through GEMM1): interm | rp_gu | smz_gu | xh   = 256,688,128 B
//   phase 2 (after GEMM1):   interm | rp_dn | smz_dn        = 191,258,624 B
extern "C" void kernel_launch(void* const* d_in, const int* in_sizes, int n_in,
                              void* d_out, int out_size, void* d_ws, size_t ws_size,
                              hipStream_t stream) {
  const float* x_f32 = (const float*)d_in[0];          // harness upcasts fp16 -> fp32
  const int* qw_gu = (const int*)d_in[1];
  const int* qz_gu = (const int*)d_in[2];
  const float* sc_gu = (const float*)d_in[3];          // fp32 (upcast)
  const int* qw_dn = (const int*)d_in[4];
  const int* qz_dn = (const int*)d_in[5];
  const float* sc_dn = (const float*)d_in[6];          // fp32 (upcast)

  char* ws = (char*)d_ws;
  __half* interm   = (__half*)ws;                      // 155,189,248
  uint32_t* rp_gu  = (uint32_t*)(ws + 155189248ull);   // 67,895,296
  uint32_t* smz_gu = (uint32_t*)(ws + 223084544ull);   // 4,243,456
  __half* xh       = (__half*)(ws + 227328000ull);     // 29,360,128
  uint32_t* rp_dn  = (uint32_t*)(ws + 155189248ull);   // aliases rp_gu
  uint32_t* smz_dn = (uint32_t*)(ws + 189136896ull);

  // ---- phase 1: prep + GEMM1 ----
  xcvt_kernel<<<14336, 256, 0, stream>>>(x_f32, xh);
  repack_kernel<<<dim3(148, 112), 256, 0, stream>>>(qw_gu, rp_gu, 4736);
  smz_kernel<<<dim3(148, 28), 256, 0, stream>>>(sc_gu, qz_gu, smz_gu, 4736);

  // GEMM1: blocks stride 128 gate cols (paired up cols at +18944)
  awq_gemm<3584, 37888, 18944, 18944, true, 2, 128>
      <<<dim3(148, 32), 256, 0, stream>>>(xh, rp_gu, smz_gu, (void*)interm);

  // ---- phase 2: prep + GEMM2 (aliased scratch) ----
  repack_kernel<<<dim3(14, 592), 256, 0, stream>>>(qw_dn, rp_dn, 448);
  smz_kernel<<<dim3(14, 148), 256, 0, stream>>>(sc_dn, qz_dn, smz_dn, 448);

  // GEMM2: blocks stride 256 cols (two adjacent 128-col tiles)
  awq_gemm<18944, 3584, 128, 3584, false, 2, 256>
      <<<dim3(14, 32), 256, 0, stream>>>(interm, rp_dn, smz_dn, d_out);
}